// Round 7
// baseline (179.320 us; speedup 1.0000x reference)
//
#include <hip/hip_runtime.h>
#include <math.h>
#include <stdint.h>

#define HC 4
#define HIDDEN 4096
#define DIM (HC * HIDDEN)          // 16384 floats per row
#define MIXN ((2 + HC) * HC)       // 24
#define RPB 8                      // rows per block
#define THREADS 256
#define NWAVE 4
#define MPW (MIXN / NWAVE)         // 6 gate columns per wave
#define CHUNK 256                  // floats per row per K-chunk (1 KB)
#define NCHUNK (DIM / CHUNK)       // 64
#define NBUF 4                     // ring buffers -> prefetch depth 3
#define NROWS (2 * 4096)           // B*S = 8192
#define HC_EPS 1e-5f
#define NORM_EPS 1e-6f

#define PRE_OFF 0
#define POST_OFF (NROWS * HC)            // 32768
#define COMB_OFF (2 * NROWS * HC)        // 65536

typedef float f32x4 __attribute__((ext_vector_type(4)));

__device__ __forceinline__ void g2lds16(const float* g, float* l) {
    // per-lane global src; LDS dest = wave-uniform base + lane*16
    __builtin_amdgcn_global_load_lds(
        (const __attribute__((address_space(1))) uint32_t*)g,
        (__attribute__((address_space(3))) uint32_t*)l, 16, 0, 0);
}

// No 2nd __launch_bounds__ arg: rounds 4/5 showed ",4" pins VGPR=64 -> massive spills.
__global__ __launch_bounds__(THREADS) void hyperconn_kernel(
    const float* __restrict__ hs,    // [NROWS][DIM]
    const float* __restrict__ fn,    // [MIXN][DIM]
    const float* __restrict__ base,  // [MIXN]
    const float* __restrict__ scale, // [3]
    float* __restrict__ out)
{
    const int tid  = threadIdx.x;
    const int wave = tid >> 6;
    const int lane = tid & 63;
    const int row0 = blockIdx.x * RPB;
    const int mg   = wave * MPW;          // this wave's first gate column

    __shared__ __align__(16) float lds[NBUF][RPB][CHUNK];   // 32 KB ring
    __shared__ float s_fin[RPB * 25];

    float acc[RPB][MPW];                  // acc[k] <-> phys row (2*wave + k) & 7
    #pragma unroll
    for (int k = 0; k < RPB; ++k)
        #pragma unroll
        for (int j = 0; j < MPW; ++j) acc[k][j] = 0.0f;
    float ssq0 = 0.0f, ssq1 = 0.0f;       // phys rows 2*wave, 2*wave+1 (== x[0], x[1])

    const f32x4* __restrict__ fn4 = reinterpret_cast<const f32x4*>(fn);

    // stage chunk t into lds[buf]: wave w stages its own two rows (1 KB each)
    auto stage = [&](int t, int buf) {
        #pragma unroll
        for (int rr = 0; rr < 2; ++rr) {
            const int r = 2 * wave + rr;
            g2lds16(hs + (size_t)(row0 + r) * DIM + t * CHUNK + lane * 4,
                    &lds[buf][r][0]);
        }
    };

    stage(0, 0); stage(1, 1); stage(2, 2);   // prefetch depth 3

    int bcur = 0;
    #pragma unroll 1
    for (int t = 0; t < NCHUNK; ++t) {
        // counted wait: own outstanding = 2 loads per staged chunk.
        // steady state {t, t+1, t+2} outstanding -> vmcnt(4) completes stage(t) only.
        if (t <= NCHUNK - 3)      asm volatile("s_waitcnt vmcnt(4)" ::: "memory");
        else if (t == NCHUNK - 2) asm volatile("s_waitcnt vmcnt(2)" ::: "memory");
        else                      asm volatile("s_waitcnt vmcnt(0)" ::: "memory");
        __builtin_amdgcn_s_barrier();      // raw barrier: no vmcnt(0) drain
        asm volatile("" ::: "memory");

        // stage 3 ahead; overwrites buf used by compute(t-1), safe after barrier(t)
        if (t + 3 < NCHUNK) {
            int bs = bcur + 3; if (bs >= NBUF) bs -= NBUF;
            stage(t + 3, bs);
        }

        // ---- compute chunk t from lds[bcur] ----
        f32x4 f[MPW];
        #pragma unroll
        for (int j = 0; j < MPW; ++j)
            f[j] = fn4[(size_t)(mg + j) * (DIM / 4) + t * (CHUNK / 4) + lane];

        #pragma unroll
        for (int g = 0; g < 2; ++g) {
            f32x4 x[RPB / 2];
            #pragma unroll
            for (int r = 0; r < RPB / 2; ++r)
                x[r] = *reinterpret_cast<const f32x4*>(
                    &lds[bcur][(2 * wave + g * (RPB / 2) + r) & 7][lane * 4]);

            if (g == 0) {  // own rows are x[0], x[1] by construction (compile-time idx)
                ssq0 = fmaf(x[0].x, x[0].x, ssq0); ssq0 = fmaf(x[0].y, x[0].y, ssq0);
                ssq0 = fmaf(x[0].z, x[0].z, ssq0); ssq0 = fmaf(x[0].w, x[0].w, ssq0);
                ssq1 = fmaf(x[1].x, x[1].x, ssq1); ssq1 = fmaf(x[1].y, x[1].y, ssq1);
                ssq1 = fmaf(x[1].z, x[1].z, ssq1); ssq1 = fmaf(x[1].w, x[1].w, ssq1);
            }

            #pragma unroll
            for (int r = 0; r < RPB / 2; ++r)
                #pragma unroll
                for (int j = 0; j < MPW; ++j) {
                    float& a = acc[g * (RPB / 2) + r][j];
                    a = fmaf(x[r].x, f[j].x, a);
                    a = fmaf(x[r].y, f[j].y, a);
                    a = fmaf(x[r].z, f[j].z, a);
                    a = fmaf(x[r].w, f[j].w, a);
                }
        }

        bcur = (bcur + 1 == NBUF) ? 0 : bcur + 1;
    }

    // 64-lane butterfly reduce: 48 dot partials + 2 ssq per wave
    #pragma unroll
    for (int k = 0; k < RPB; ++k)
        #pragma unroll
        for (int j = 0; j < MPW; ++j) {
            float v = acc[k][j];
            #pragma unroll
            for (int off = 32; off >= 1; off >>= 1) v += __shfl_xor(v, off, 64);
            acc[k][j] = v;
        }
    #pragma unroll
    for (int off = 32; off >= 1; off >>= 1) ssq0 += __shfl_xor(ssq0, off, 64);
    #pragma unroll
    for (int off = 32; off >= 1; off >>= 1) ssq1 += __shfl_xor(ssq1, off, 64);

    if (lane == 0) {
        #pragma unroll
        for (int k = 0; k < RPB; ++k) {
            const int pr = (2 * wave + k) & 7;     // runtime LDS addr: fine
            #pragma unroll
            for (int j = 0; j < MPW; ++j) s_fin[pr * 25 + mg + j] = acc[k][j];
        }
        s_fin[(2 * wave) * 25 + 24]     = ssq0;
        s_fin[(2 * wave + 1) * 25 + 24] = ssq1;
    }
    __syncthreads();

    // epilogue: one thread per row
    if (tid < RPB) {
        const int row = row0 + tid;
        const float* v = &s_fin[tid * 25];
        const float rs = 1.0f / sqrtf(v[24] * (1.0f / (float)DIM) + NORM_EPS);
        const float s0 = scale[0], s1 = scale[1], s2 = scale[2];

        #pragma unroll
        for (int i = 0; i < HC; ++i) {
            const float z = v[i] * rs * s0 + base[i];
            out[PRE_OFF + row * HC + i] = 1.0f / (1.0f + expf(-z)) + HC_EPS;
        }
        #pragma unroll
        for (int i = 0; i < HC; ++i) {
            const float z = v[HC + i] * rs * s1 + base[HC + i];
            out[POST_OFF + row * HC + i] = 2.0f / (1.0f + expf(-z));
        }

        float c[HC][HC];
        #pragma unroll
        for (int i = 0; i < HC; ++i) {
            float l[HC];
            #pragma unroll
            for (int j = 0; j < HC; ++j)
                l[j] = v[2 * HC + i * HC + j] * rs * s2 + base[2 * HC + i * HC + j];
            const float mx = fmaxf(fmaxf(l[0], l[1]), fmaxf(l[2], l[3]));
            float e[HC];
            float sum = 0.0f;
            #pragma unroll
            for (int j = 0; j < HC; ++j) { e[j] = expf(l[j] - mx); sum += e[j]; }
            const float inv = 1.0f / sum;
            #pragma unroll
            for (int j = 0; j < HC; ++j) c[i][j] = e[j] * inv + HC_EPS;
        }
        #pragma unroll
        for (int j = 0; j < HC; ++j) {
            const float cs = c[0][j] + c[1][j] + c[2][j] + c[3][j] + HC_EPS;
            const float inv = 1.0f / cs;
            c[0][j] *= inv; c[1][j] *= inv; c[2][j] *= inv; c[3][j] *= inv;
        }
        #pragma unroll
        for (int it = 0; it < 4; ++it) {
            #pragma unroll
            for (int i = 0; i < HC; ++i) {
                const float rsum = c[i][0] + c[i][1] + c[i][2] + c[i][3] + HC_EPS;
                const float inv = 1.0f / rsum;
                c[i][0] *= inv; c[i][1] *= inv; c[i][2] *= inv; c[i][3] *= inv;
            }
            #pragma unroll
            for (int j = 0; j < HC; ++j) {
                const float cs = c[0][j] + c[1][j] + c[2][j] + c[3][j] + HC_EPS;
                const float inv = 1.0f / cs;
                c[0][j] *= inv; c[1][j] *= inv; c[2][j] *= inv; c[3][j] *= inv;
            }
        }
        #pragma unroll
        for (int i = 0; i < HC; ++i)
            #pragma unroll
            for (int j = 0; j < HC; ++j)
                out[COMB_OFF + row * (HC * HC) + i * HC + j] = c[i][j];
    }
}

extern "C" void kernel_launch(void* const* d_in, const int* in_sizes, int n_in,
                              void* d_out, int out_size, void* d_ws, size_t ws_size,
                              hipStream_t stream) {
    const float* hs    = (const float*)d_in[0];
    const float* fn    = (const float*)d_in[1];
    const float* base  = (const float*)d_in[2];
    const float* scale = (const float*)d_in[3];
    float* out = (float*)d_out;

    const int grid = NROWS / RPB;  // 1024 blocks, 4/CU -> fully co-resident, no tail
    hyperconn_kernel<<<grid, THREADS, 0, stream>>>(hs, fn, base, scale, out);
}

// Round 8
// 179.098 us; speedup vs baseline: 1.0012x; 1.0012x over previous
//
#include <hip/hip_runtime.h>
#include <math.h>
#include <stdint.h>

#define HC 4
#define HIDDEN 4096
#define DIM (HC * HIDDEN)          // 16384 floats per row
#define MIXN ((2 + HC) * HC)       // 24
#define RPB 16                     // rows per block
#define THREADS 512
#define NWAVE 8
#define MPW (MIXN / NWAVE)         // 3 gate columns per wave
#define CHUNK 256                  // floats per row per K-chunk (1 KB)
#define NCHUNK (DIM / CHUNK)       // 64
#define NBUF 4                     // ring buffers -> prefetch depth 3
#define NROWS (2 * 4096)           // B*S = 8192
#define HC_EPS 1e-5f
#define NORM_EPS 1e-6f

#define PRE_OFF 0
#define POST_OFF (NROWS * HC)            // 32768
#define COMB_OFF (2 * NROWS * HC)        // 65536

typedef float f32x4 __attribute__((ext_vector_type(4)));

__device__ __forceinline__ void g2lds16_nt(const float* g, float* l) {
    // per-lane global src; LDS dest = wave-uniform base + lane*16.
    // aux=2 -> NT (evict-first in L2): the hs stream must not thrash fn's residency.
    __builtin_amdgcn_global_load_lds(
        (const __attribute__((address_space(1))) uint32_t*)g,
        (__attribute__((address_space(3))) uint32_t*)l, 16, 0, 2);
}

// No 2nd __launch_bounds__ arg: rounds 4/5 showed ",4" pins VGPR=64 -> massive spills.
__global__ __launch_bounds__(THREADS) void hyperconn_kernel(
    const float* __restrict__ hs,    // [NROWS][DIM]
    const float* __restrict__ fn,    // [MIXN][DIM]
    const float* __restrict__ base,  // [MIXN]
    const float* __restrict__ scale, // [3]
    float* __restrict__ out)
{
    const int tid  = threadIdx.x;
    const int wave = tid >> 6;
    const int lane = tid & 63;
    const int row0 = blockIdx.x * RPB;
    const int mg   = wave * MPW;          // this wave's first gate column

    __shared__ __align__(16) float lds[NBUF][RPB][CHUNK];   // 64 KB ring
    __shared__ float s_fin[RPB * 25];

    float acc[RPB][MPW];                  // acc[k] <-> phys row (2*wave + k) & 15
    #pragma unroll
    for (int k = 0; k < RPB; ++k)
        #pragma unroll
        for (int j = 0; j < MPW; ++j) acc[k][j] = 0.0f;
    float ssq0 = 0.0f, ssq1 = 0.0f;       // phys rows 2*wave, 2*wave+1 (== x[0], x[1] at g=0)

    const f32x4* __restrict__ fn4 = reinterpret_cast<const f32x4*>(fn);

    // stage chunk t into lds[buf]: wave w stages its own two rows (1 KB each)
    auto stage = [&](int t, int buf) {
        #pragma unroll
        for (int rr = 0; rr < 2; ++rr) {
            const int r = 2 * wave + rr;
            g2lds16_nt(hs + (size_t)(row0 + r) * DIM + t * CHUNK + lane * 4,
                       &lds[buf][r][0]);
        }
    };

    stage(0, 0); stage(1, 1); stage(2, 2);   // prefetch depth 3

    int bcur = 0;
    #pragma unroll 1
    for (int t = 0; t < NCHUNK; ++t) {
        // counted wait: 2 own loads per staged chunk; steady state {t,t+1,t+2} = 6
        // outstanding -> vmcnt(4) completes stage(t) only (fn loads already drained
        // by their FMA uses within the previous iteration).
        if (t <= NCHUNK - 3)      asm volatile("s_waitcnt vmcnt(4)" ::: "memory");
        else if (t == NCHUNK - 2) asm volatile("s_waitcnt vmcnt(2)" ::: "memory");
        else                      asm volatile("s_waitcnt vmcnt(0)" ::: "memory");
        __builtin_amdgcn_s_barrier();      // raw barrier: no vmcnt(0) drain
        asm volatile("" ::: "memory");

        // stage 3 ahead; overwrites buf used by compute(t-1), safe after barrier(t)
        if (t + 3 < NCHUNK) {
            int bs = bcur + 3; if (bs >= NBUF) bs -= NBUF;
            stage(t + 3, bs);
        }

        // ---- compute chunk t from lds[bcur] ----
        f32x4 f[MPW];
        #pragma unroll
        for (int j = 0; j < MPW; ++j)
            f[j] = fn4[(size_t)(mg + j) * (DIM / 4) + t * (CHUNK / 4) + lane];

        #pragma unroll
        for (int g = 0; g < 4; ++g) {
            f32x4 x[4];
            #pragma unroll
            for (int r = 0; r < 4; ++r)
                x[r] = *reinterpret_cast<const f32x4*>(
                    &lds[bcur][(2 * wave + g * 4 + r) & 15][lane * 4]);

            if (g == 0) {  // own rows are x[0], x[1] by construction (compile-time idx)
                ssq0 = fmaf(x[0].x, x[0].x, ssq0); ssq0 = fmaf(x[0].y, x[0].y, ssq0);
                ssq0 = fmaf(x[0].z, x[0].z, ssq0); ssq0 = fmaf(x[0].w, x[0].w, ssq0);
                ssq1 = fmaf(x[1].x, x[1].x, ssq1); ssq1 = fmaf(x[1].y, x[1].y, ssq1);
                ssq1 = fmaf(x[1].z, x[1].z, ssq1); ssq1 = fmaf(x[1].w, x[1].w, ssq1);
            }

            #pragma unroll
            for (int r = 0; r < 4; ++r)
                #pragma unroll
                for (int j = 0; j < MPW; ++j) {
                    float& a = acc[g * 4 + r][j];
                    a = fmaf(x[r].x, f[j].x, a);
                    a = fmaf(x[r].y, f[j].y, a);
                    a = fmaf(x[r].z, f[j].z, a);
                    a = fmaf(x[r].w, f[j].w, a);
                }
        }

        bcur = (bcur + 1 == NBUF) ? 0 : bcur + 1;
    }

    // 64-lane butterfly reduce: 48 dot partials + 2 ssq per wave
    #pragma unroll
    for (int k = 0; k < RPB; ++k)
        #pragma unroll
        for (int j = 0; j < MPW; ++j) {
            float v = acc[k][j];
            #pragma unroll
            for (int off = 32; off >= 1; off >>= 1) v += __shfl_xor(v, off, 64);
            acc[k][j] = v;
        }
    #pragma unroll
    for (int off = 32; off >= 1; off >>= 1) ssq0 += __shfl_xor(ssq0, off, 64);
    #pragma unroll
    for (int off = 32; off >= 1; off >>= 1) ssq1 += __shfl_xor(ssq1, off, 64);

    if (lane == 0) {
        #pragma unroll
        for (int k = 0; k < RPB; ++k) {
            const int pr = (2 * wave + k) & 15;    // runtime LDS addr: fine
            #pragma unroll
            for (int j = 0; j < MPW; ++j) s_fin[pr * 25 + mg + j] = acc[k][j];
        }
        s_fin[(2 * wave) * 25 + 24]     = ssq0;
        s_fin[(2 * wave + 1) * 25 + 24] = ssq1;
    }
    __syncthreads();

    // epilogue: one thread per row
    if (tid < RPB) {
        const int row = row0 + tid;
        const float* v = &s_fin[tid * 25];
        const float rs = 1.0f / sqrtf(v[24] * (1.0f / (float)DIM) + NORM_EPS);
        const float s0 = scale[0], s1 = scale[1], s2 = scale[2];

        #pragma unroll
        for (int i = 0; i < HC; ++i) {
            const float z = v[i] * rs * s0 + base[i];
            out[PRE_OFF + row * HC + i] = 1.0f / (1.0f + expf(-z)) + HC_EPS;
        }
        #pragma unroll
        for (int i = 0; i < HC; ++i) {
            const float z = v[HC + i] * rs * s1 + base[HC + i];
            out[POST_OFF + row * HC + i] = 2.0f / (1.0f + expf(-z));
        }

        float c[HC][HC];
        #pragma unroll
        for (int i = 0; i < HC; ++i) {
            float l[HC];
            #pragma unroll
            for (int j = 0; j < HC; ++j)
                l[j] = v[2 * HC + i * HC + j] * rs * s2 + base[2 * HC + i * HC + j];
            const float mx = fmaxf(fmaxf(l[0], l[1]), fmaxf(l[2], l[3]));
            float e[HC];
            float sum = 0.0f;
            #pragma unroll
            for (int j = 0; j < HC; ++j) { e[j] = expf(l[j] - mx); sum += e[j]; }
            const float inv = 1.0f / sum;
            #pragma unroll
            for (int j = 0; j < HC; ++j) c[i][j] = e[j] * inv + HC_EPS;
        }
        #pragma unroll
        for (int j = 0; j < HC; ++j) {
            const float cs = c[0][j] + c[1][j] + c[2][j] + c[3][j] + HC_EPS;
            const float inv = 1.0f / cs;
            c[0][j] *= inv; c[1][j] *= inv; c[2][j] *= inv; c[3][j] *= inv;
        }
        #pragma unroll
        for (int it = 0; it < 4; ++it) {
            #pragma unroll
            for (int i = 0; i < HC; ++i) {
                const float rsum = c[i][0] + c[i][1] + c[i][2] + c[i][3] + HC_EPS;
                const float inv = 1.0f / rsum;
                c[i][0] *= inv; c[i][1] *= inv; c[i][2] *= inv; c[i][3] *= inv;
            }
            #pragma unroll
            for (int j = 0; j < HC; ++j) {
                const float cs = c[0][j] + c[1][j] + c[2][j] + c[3][j] + HC_EPS;
                const float inv = 1.0f / cs;
                c[0][j] *= inv; c[1][j] *= inv; c[2][j] *= inv; c[3][j] *= inv;
            }
        }
        #pragma unroll
        for (int i = 0; i < HC; ++i)
            #pragma unroll
            for (int j = 0; j < HC; ++j)
                out[COMB_OFF + row * (HC * HC) + i * HC + j] = c[i][j];
    }
}

extern "C" void kernel_launch(void* const* d_in, const int* in_sizes, int n_in,
                              void* d_out, int out_size, void* d_ws, size_t ws_size,
                              hipStream_t stream) {
    const float* hs    = (const float*)d_in[0];
    const float* fn    = (const float*)d_in[1];
    const float* base  = (const float*)d_in[2];
    const float* scale = (const float*)d_in[3];
    float* out = (float*)d_out;

    const int grid = NROWS / RPB;  // 512 blocks, 2/CU -> fully co-resident, no tail
    hyperconn_kernel<<<grid, THREADS, 0, stream>>>(hs, fn, base, scale, out);
}